// Round 10
// baseline (900.787 us; speedup 1.0000x reference)
//
#include <hip/hip_runtime.h>
#include <hip/hip_bf16.h>
#include <math.h>

#define N_NODES 50000
#define M_PAD   50048   // 782 * 64 = 391 * 128
#define N_EDGES 800000
#define N_GRAPHS 100
#define IN_DIM 100
#define D 128
#define N_STEPS 8
#define NBINS (N_NODES * 4)      // (dst, type) bins
#define SCAN_BLOCKS 196          // 196*1024 = 200704 >= NBINS

typedef unsigned short ushort_t;
typedef __bf16 bf16x8 __attribute__((ext_vector_type(8)));
typedef float f32x4 __attribute__((ext_vector_type(4)));

__device__ inline ushort_t f2b(float f) {
  __hip_bfloat16 b = __float2bfloat16(f);
  return *reinterpret_cast<ushort_t*>(&b);
}
__device__ inline float b2f(unsigned int u16) {
  unsigned int x = u16 << 16;
  return __builtin_bit_cast(float, x);
}

// async global->LDS, 16B per lane; lds dest = wave-uniform base + lane*16.
__device__ __attribute__((always_inline)) inline void gld16(const ushort_t* g, ushort_t* l) {
  __builtin_amdgcn_global_load_lds(
      (const __attribute__((address_space(1))) void*)g,
      (__attribute__((address_space(3))) void*)l, 16, 0, 0);
}

// Dense bf16 state arrays h[N][128], a[N][128] (256B rows).
// Rounds 16 & 18 proved fusion regresses (barrier coupling / collapsed block
// parallelism on latency-bound kernels). Keep 3-kernel step structure.
__global__ void pad_cast_kernel(const float* __restrict__ feat, ushort_t* __restrict__ h) {
  int idx = blockIdx.x * blockDim.x + threadIdx.x;
  if (idx >= N_NODES * D) return;
  int n = idx >> 7, d = idx & 127;
  float v = (d < IN_DIM) ? feat[n * IN_DIM + d] : 0.0f;
  h[(size_t)n * 128 + d] = f2b(v);
}

// BtS[f][t*128+k] = bf16(W_msg[t][k][f])   (n-major, k-contiguous, K=512)
__global__ void prep_bts(const float* __restrict__ W_msg, ushort_t* __restrict__ BtS) {
  int idx = blockIdx.x * blockDim.x + threadIdx.x;
  if (idx >= 128 * 512) return;
  int f = idx >> 9, kp = idx & 511;
  int t = kp >> 7, k = kp & 127;
  BtS[(size_t)f * 512 + kp] = f2b(W_msg[((size_t)t * 128 + k) * 128 + f]);
}

// Permuted fused GRU weight, n-major k-contiguous bf16.
// col' = g*64 + gate*16 + r ; dim d = g*16 + r ; K: k<128 = a (W_ih), k>=128 = h (W_hh)
__global__ void prep_wg(const float* __restrict__ W_ih, const float* __restrict__ W_hh,
                        const float* __restrict__ b_ih, const float* __restrict__ b_hh,
                        ushort_t* __restrict__ WgT, float* __restrict__ gbias) {
  int idx = blockIdx.x * blockDim.x + threadIdx.x;
  if (idx >= 512 * 256) return;
  int colp = idx >> 8, k = idx & 255;
  int g = colp >> 6, gate = (colp >> 4) & 3, r = colp & 15;
  int d = g * 16 + r;
  float v;
  if (gate == 3)      v = (k < 128) ? 0.f : W_hh[(size_t)(256 + d) * 128 + (k - 128)];
  else if (gate == 2) v = (k < 128) ? W_ih[(size_t)(256 + d) * 128 + k] : 0.f;
  else {
    int j0 = (gate == 0) ? d : 128 + d;
    v = (k < 128) ? W_ih[(size_t)j0 * 128 + k] : W_hh[(size_t)j0 * 128 + (k - 128)];
  }
  WgT[(size_t)colp * 256 + k] = f2b(v);
  if (k == 0) {
    float bb = (gate == 0) ? b_ih[d] + b_hh[d]
             : (gate == 1) ? b_ih[128 + d] + b_hh[128 + d]
             : (gate == 2) ? b_ih[256 + d] : b_hh[256 + d];
    gbias[colp] = bb;
  }
}

// ---- type-segmented CSR build over NBINS = dst*4+type ----
__global__ void hist_kernel(const int* __restrict__ edst, const int* __restrict__ etype,
                            int* __restrict__ cnt2, int* __restrict__ rank) {
  int e = blockIdx.x * 256 + threadIdx.x;
  if (e >= N_EDGES) return;
  rank[e] = atomicAdd(&cnt2[edst[e] * 4 + etype[e]], 1);
}

// 3-phase scan: A) per-block inclusive scan + block sums
__global__ __launch_bounds__(1024) void scanA(const int* __restrict__ cnt2,
                                              int* __restrict__ tmp, int* __restrict__ bsum) {
  __shared__ int wsum[16];
  int b = blockIdx.x, t = threadIdx.x;
  int i = b * 1024 + t;
  int lane = t & 63, wid = t >> 6;
  int x = (i < NBINS) ? cnt2[i] : 0;
  #pragma unroll
  for (int s = 1; s < 64; s <<= 1) {
    int y = __shfl_up(x, s, 64);
    if (lane >= s) x += y;
  }
  if (lane == 63) wsum[wid] = x;
  __syncthreads();
  if (wid == 0) {
    int w = (lane < 16) ? wsum[lane] : 0;
    #pragma unroll
    for (int s = 1; s < 16; s <<= 1) {
      int y = __shfl_up(w, s, 64);
      if (lane >= s) w += y;
    }
    if (lane < 16) wsum[lane] = w;
  }
  __syncthreads();
  int wb = (wid > 0) ? wsum[wid - 1] : 0;
  tmp[i] = wb + x;
  if (t == 1023) bsum[b] = wsum[15];
}

// B) one wave scans the SCAN_BLOCKS block sums -> exclusive prefixes
__global__ __launch_bounds__(64) void scanB(const int* __restrict__ bsum,
                                            int* __restrict__ bpre) {
  int lane = threadIdx.x;
  int carry = 0;
  for (int base = 0; base < SCAN_BLOCKS; base += 64) {
    int idx = base + lane;
    int v = (idx < SCAN_BLOCKS) ? bsum[idx] : 0;
    int x = v;
    #pragma unroll
    for (int s = 1; s < 64; s <<= 1) {
      int y = __shfl_up(x, s, 64);
      if (lane >= s) x += y;
    }
    if (idx < SCAN_BLOCKS) bpre[idx] = carry + x - v;
    carry += __shfl(x, 63, 64);
  }
}

// C) offs2[i+1] = tmp[i] + bpre[block]
__global__ __launch_bounds__(1024) void scanC(const int* __restrict__ tmp,
                                              const int* __restrict__ bpre,
                                              int* __restrict__ offs2) {
  int b = blockIdx.x, t = threadIdx.x;
  int i = b * 1024 + t;
  if (i < NBINS) offs2[i + 1] = tmp[i] + bpre[b];
  if (i == 0) offs2[0] = 0;
}

__global__ void fill_kernel(const int* __restrict__ esrc, const int* __restrict__ edst,
                            const int* __restrict__ etype, const int* __restrict__ offs2,
                            const int* __restrict__ rank, int* __restrict__ payload) {
  int e = blockIdx.x * 256 + threadIdx.x;
  if (e >= N_EDGES) return;
  int key = edst[e] * 4 + etype[e];
  payload[offs2[key] + rank[e]] = esrc[e];
}

// ROUND-6 gather, FROZEN. One wave per node, 12500 tiny blocks. Three failed
// variants: r16/r18 fusion (barrier coupling kills MLP), r21 persistent grid
// (lost churn-based load balancing: occupancy 61->54, dur +2us). The tiny
// blocks ARE the load balancer. At the random-access ceiling. Do not touch.
__global__ __launch_bounds__(256) void gather_kernel(const int* __restrict__ offs2,
    const int* __restrict__ payload, const ushort_t* __restrict__ hb,
    ushort_t* __restrict__ S, float* __restrict__ cntf) {
  int n = blockIdx.x * 4 + (threadIdx.x >> 6);
  int lane = threadIdx.x & 63;
  if (n >= N_NODES) return;
  int bb[5];
  #pragma unroll
  for (int k = 0; k < 5; ++k) bb[k] = offs2[n * 4 + k];
  float a[4][2] = {{0.f, 0.f}, {0.f, 0.f}, {0.f, 0.f}, {0.f, 0.f}};
  const ushort_t* hrow = hb + lane * 2;
  for (int base = bb[0]; base < bb[4]; base += 64) {
    int lim = min(bb[4], base + 64);
    int cnt = lim - base;
    int pe = (lane < cnt) ? payload[base + lane] : 0;
    #pragma unroll
    for (int t = 0; t < 4; ++t) {
      int lo = max(bb[t], base), hi = min(bb[t + 1], lim);
      int i = lo;
      for (; i + 4 <= hi; i += 4) {
        int s0 = __shfl(pe, i - base, 64);
        int s1 = __shfl(pe, i + 1 - base, 64);
        int s2 = __shfl(pe, i + 2 - base, 64);
        int s3 = __shfl(pe, i + 3 - base, 64);
        unsigned int u0 = *(const unsigned int*)(hrow + (size_t)s0 * 128);
        unsigned int u1 = *(const unsigned int*)(hrow + (size_t)s1 * 128);
        unsigned int u2 = *(const unsigned int*)(hrow + (size_t)s2 * 128);
        unsigned int u3 = *(const unsigned int*)(hrow + (size_t)s3 * 128);
        a[t][0] += b2f(u0 & 0xffff) + b2f(u1 & 0xffff) + b2f(u2 & 0xffff) + b2f(u3 & 0xffff);
        a[t][1] += b2f(u0 >> 16) + b2f(u1 >> 16) + b2f(u2 >> 16) + b2f(u3 >> 16);
      }
      for (; i < hi; ++i) {
        int s0 = __shfl(pe, i - base, 64);
        unsigned int u0 = *(const unsigned int*)(hrow + (size_t)s0 * 128);
        a[t][0] += b2f(u0 & 0xffff);
        a[t][1] += b2f(u0 >> 16);
      }
    }
  }
  #pragma unroll
  for (int t = 0; t < 4; ++t) {
    unsigned int packed = (unsigned int)f2b(a[t][0]) | ((unsigned int)f2b(a[t][1]) << 16);
    *(unsigned int*)(S + (size_t)n * 512 + t * 128 + lane * 2) = packed;
    if (lane == 0) cntf[n * 4 + t] = (float)(bb[t + 1] - bb[t]);
  }
}

// ---- msg GEMM: 128(M)x128(N) tile, 8 waves (512 thr), K=512 (round 19). ----
// XCD chunk swizzle (391 = 8*48+7) aligning each XCD's a-writes with the
// m-chunks the gru on that XCD will read (a = 1.6 MB/XCD -> L2-resident).
__global__ __launch_bounds__(512, 4) void mfma_msg(
    const ushort_t* __restrict__ S,
    const ushort_t* __restrict__ Bt,
    const float* __restrict__ b_msg, const float* __restrict__ cntf,
    ushort_t* __restrict__ a_out) {
  constexpr int K = 512;
  constexpr int NT  = K / 32;     // 16 k-steps
  constexpr int PRE = 3;
  constexpr int SLOT = 16384;
  __shared__ __align__(16) unsigned char smem[SLOT * 4];   // 64 KB
  int orig = blockIdx.x;
  int xcd = orig & 7, sidx = orig >> 3;
  int wgb = (xcd < 7) ? (xcd * 49 + sidx) : (343 + sidx);
  const int m0 = wgb * 128;
  int tid = threadIdx.x;
  int wave = tid >> 6, lane = tid & 63;
  int wm = (wave & 3) * 32, wn = (wave >> 2) * 64;
  int quad = lane >> 4, l16 = lane & 15;

  int sr = lane >> 2, sc = lane & 3;
  const ushort_t* gA = S  + (size_t)(m0 + wave * 16 + sr) * K + sc * 8;
  const ushort_t* gB = Bt + (size_t)(wave * 16 + sr) * K + sc * 8;

  auto stage = [&](int slot, int t) {
    ushort_t* base = (ushort_t*)(smem + slot * SLOT);
    int k0 = t * 32;
    gld16(gA + k0, base + wave * 512);            // A rows wave*16..+16
    gld16(gB + k0, base + 4096 + wave * 512);     // B rows wave*16..+16
  };

  f32x4 acc[2][4];
  #pragma unroll
  for (int i = 0; i < 2; ++i)
    #pragma unroll
    for (int j = 0; j < 4; ++j) acc[i][j] = (f32x4){0.f, 0.f, 0.f, 0.f};

  #pragma unroll
  for (int t = 0; t < PRE; ++t) stage(t, t);

  #pragma unroll
  for (int t = 0; t < NT; ++t) {
    int infl = NT - 1 - t;
    if (infl >= 2)      asm volatile("s_waitcnt vmcnt(4) lgkmcnt(0)" ::: "memory");
    else if (infl == 1) asm volatile("s_waitcnt vmcnt(2) lgkmcnt(0)" ::: "memory");
    else                asm volatile("s_waitcnt vmcnt(0) lgkmcnt(0)" ::: "memory");
    __builtin_amdgcn_s_barrier();
    if (t + PRE < NT) stage((t + PRE) & 3, t + PRE);
    const ushort_t* As = (const ushort_t*)(smem + (t & 3) * SLOT);
    const ushort_t* Bs = As + 4096;
    bf16x8 af[2], bfr[4];
    #pragma unroll
    for (int i = 0; i < 2; ++i) af[i] = *(const bf16x8*)&As[(wm + i * 16 + l16) * 32 + quad * 8];
    #pragma unroll
    for (int j = 0; j < 4; ++j) bfr[j] = *(const bf16x8*)&Bs[(wn + j * 16 + l16) * 32 + quad * 8];
    #pragma unroll
    for (int i = 0; i < 2; ++i)
      #pragma unroll
      for (int j = 0; j < 4; ++j)
        acc[i][j] = __builtin_amdgcn_mfma_f32_16x16x32_bf16(af[i], bfr[j], acc[i][j], 0, 0, 0);
  }
  // Ep spans 34.8KB (slots 0-2): safe -- at last-iter entry lgkmcnt(0)+barrier
  // drained all reads of tiles <= NT-2; in-flight ds_reads target slot 3 only.
  ushort_t* Ep = (ushort_t*)smem;   // [128][136]
  float bm[4][4];  // [j][t]
  #pragma unroll
  for (int j = 0; j < 4; ++j)
    #pragma unroll
    for (int t = 0; t < 4; ++t)
      bm[j][t] = b_msg[t * 128 + wn + j * 16 + l16];
  #pragma unroll
  for (int i = 0; i < 2; ++i)
    #pragma unroll
    for (int reg = 0; reg < 4; ++reg) {
      int row = wm + i * 16 + quad * 4 + reg;
      float4 c = *(const float4*)(cntf + (size_t)(m0 + row) * 4);
      #pragma unroll
      for (int j = 0; j < 4; ++j) {
        float val = acc[i][j][reg] + c.x * bm[j][0] + c.y * bm[j][1]
                                   + c.z * bm[j][2] + c.w * bm[j][3];
        Ep[row * 136 + wn + j * 16 + l16] = f2b(val);
      }
    }
  __syncthreads();
  #pragma unroll
  for (int c2 = 0; c2 < 4; ++c2) {
    int chunk = tid + 512 * c2;            // 2048 x 16B = 128 rows x 256B
    int row = chunk >> 4, sub = chunk & 15;
    *(uint4*)(a_out + (size_t)(m0 + row) * 128 + sub * 8) =
        *(const uint4*)&Ep[row * 136 + sub * 8];
  }
}

// ---- ROUND-24 GRU GEMM: 128(M) x 256(gate-N) tile, 8 waves (4Mx2N). ----
// Round-9 design with the one-line correctness fix: slot layout is
// A = 8KB = 4096 USHORTS, so the compute-side B base is As + 4096 (ushorts).
// Round-9 had As + 2048 (a bytes-vs-ushorts slip) -> read A rows 64-127 as B
// -> absmax 3.5e-2 fail.
// Per k-step 3 loads (1 A + 2 B) buy 16 MFMA/wave (2x round-8's ratio);
// A staged 2x total (was 4x). Slot 24KB; 3-slot ring 72KB -> 2 blocks/CU.
// Grid 391x2 = 782 flattened, bijective XCD swizzle (782 = 8*97+6).
// K-permutation: a-tiles 0-3 first, then the two NOT-needed h-tiles, then the
// two needed h-tiles LAST (t=6 -> slot 0, t=7 -> slot 1 at exit); h_old for
// dim-half wc reads slot wc's A-region. vmcnt: 3 loads/step -> steady
// vmcnt(3), tail 0. (k-sum order-independent; fp32 reorder ~2^-20.)
__global__ __launch_bounds__(512, 4) void mfma_gru(
    const ushort_t* __restrict__ Aa, const ushort_t* __restrict__ Ah,
    const ushort_t* __restrict__ Bt,
    const float* __restrict__ bias,
    ushort_t* __restrict__ h_out) {
  constexpr int K = 256;
  constexpr int NT  = K / 32;     // 8 k-steps
  constexpr int SLOT = 24576;     // A 8KB + B 16KB
  __shared__ __align__(16) unsigned char smem[SLOT * 3];   // 72 KB
  // bijective XCD swizzle over 782 blocks: q=97, r=6.
  int orig = blockIdx.x;
  int xcd = orig & 7, idxb = orig >> 3;
  int wgid = (xcd < 6 ? xcd * 98 : 6 * 98 + (xcd - 6) * 97) + idxb;
  const int m0 = (wgid >> 1) * 128;
  const int nt = wgid & 1;        // n-tile: gate-cols [nt*256, nt*256+256)
  const int n0 = nt * 256;
  int tid = threadIdx.x;
  int wave = tid >> 6, lane = tid & 63;
  int wm = (wave & 3) * 32;       // 4 M-waves x 32 rows
  int wc = wave >> 2;             // 2 N-waves x 128 gate-cols
  int quad = lane >> 4, l16 = lane & 15;

  int sr = lane >> 2, sc = lane & 3;
  const ushort_t* gAa = Aa + (size_t)(m0 + wave * 16 + sr) * 128 + sc * 8;
  const ushort_t* gAh = Ah + (size_t)(m0 + wave * 16 + sr) * 128 + sc * 8;
  const ushort_t* gB  = Bt + (size_t)(n0 + wave * 32 + sr) * K + sc * 8;
  const ushort_t* gB2 = gB + (size_t)16 * K;

  // permuted k order (block-uniform): t<4 -> a-tile t. Needed h-tiles are
  // global {4,5} for nt=0 (h cols 0..63) and {6,7} for nt=1 (64..127).
  // nt=0: t=4..7 -> 6,7,4,5 ; nt=1: natural 4,5,6,7.
  auto kglob = [&](int t) -> int {
    if (t < 4) return t;
    if (nt) return t;
    return (t < 6) ? t + 2 : t - 2;
  };

  auto stage = [&](int slot, int t) {
    ushort_t* base = (ushort_t*)(smem + slot * SLOT);
    int kg = kglob(t);
    const ushort_t* srcA = (kg < 4) ? (gAa + kg * 32) : (gAh + (kg - 4) * 32);
    gld16(srcA, base + wave * 512);                    // A: 128 rows x 64B
    gld16(gB + kg * 32, base + 4096 + wave * 1024);    // B rows wave*32..+16
    gld16(gB2 + kg * 32, base + 4096 + wave * 1024 + 512);  // +16..+32
  };

  f32x4 acc[2][8];
  #pragma unroll
  for (int i = 0; i < 2; ++i)
    #pragma unroll
    for (int j = 0; j < 8; ++j) acc[i][j] = (f32x4){0.f, 0.f, 0.f, 0.f};

  stage(0, 0);
  stage(1, 1);

  #pragma unroll
  for (int t = 0; t < NT; ++t) {
    if (t < NT - 1) asm volatile("s_waitcnt vmcnt(3) lgkmcnt(0)" ::: "memory");
    else            asm volatile("s_waitcnt vmcnt(0) lgkmcnt(0)" ::: "memory");
    __builtin_amdgcn_s_barrier();
    if (t + 2 < NT) stage((t + 2) % 3, t + 2);
    const ushort_t* As = (const ushort_t*)(smem + (t % 3) * SLOT);
    const ushort_t* Bs = As + 4096;   // A region = 8KB = 4096 ushorts (r24 fix)
    bf16x8 af[2], bfr[8];
    #pragma unroll
    for (int i = 0; i < 2; ++i) af[i] = *(const bf16x8*)&As[(wm + i * 16 + l16) * 32 + quad * 8];
    #pragma unroll
    for (int j = 0; j < 8; ++j)
      bfr[j] = *(const bf16x8*)&Bs[(wc * 128 + j * 16 + l16) * 32 + quad * 8];
    #pragma unroll
    for (int i = 0; i < 2; ++i)
      #pragma unroll
      for (int j = 0; j < 8; ++j)
        acc[i][j] = __builtin_amdgcn_mfma_f32_16x16x32_bf16(af[i], bfr[j], acc[i][j], 0, 0, 0);
  }

  // h_old: lane's dims d_rel = (wc*2+gl)*16 + l16 (gl=0,1) live in h k-tile
  // (wc) of this block's pair -> staged LAST (t=6+wc) -> slot (6+wc)%3 = wc.
  // Within the slot A-region: row*32 + gl*16 + l16.
  float hold_r[2][4][2];
  #pragma unroll
  for (int gl = 0; gl < 2; ++gl) {
    const ushort_t* Hs = (const ushort_t*)(smem + wc * SLOT);
    #pragma unroll
    for (int i = 0; i < 2; ++i)
      #pragma unroll
      for (int reg = 0; reg < 4; ++reg) {
        int r_loc = wm + i * 16 + quad * 4 + reg;
        hold_r[i][reg][gl] = b2f(Hs[r_loc * 32 + gl * 16 + l16]);
      }
  }
  asm volatile("s_waitcnt lgkmcnt(0)" ::: "memory");
  __builtin_amdgcn_s_barrier();   // all h_old reads done before Ap overwrites

  // Gate epilogue. gbase = n0/64 + wc*2; j = gl*4 + gate.
  // Output dims per (lane,row): d = (gbase+gl)*16 + l16.
  ushort_t* Ap = (ushort_t*)smem;                 // [128][72] us = 18.4KB (slot 0)
  int gbase = (n0 >> 6) + wc * 2;
  float bs[2][4];
  #pragma unroll
  for (int gl = 0; gl < 2; ++gl)
    #pragma unroll
    for (int gate = 0; gate < 4; ++gate)
      bs[gl][gate] = bias[(gbase + gl) * 64 + gate * 16 + l16];
  #pragma unroll
  for (int i = 0; i < 2; ++i)
    #pragma unroll
    for (int reg = 0; reg < 4; ++reg) {
      int r_loc = wm + i * 16 + quad * 4 + reg;
      #pragma unroll
      for (int gl = 0; gl < 2; ++gl) {
        float pr  = acc[i][gl * 4 + 0][reg] + bs[gl][0];
        float pz  = acc[i][gl * 4 + 1][reg] + bs[gl][1];
        float in_ = acc[i][gl * 4 + 2][reg] + bs[gl][2];
        float hn  = acc[i][gl * 4 + 3][reg] + bs[gl][3];
        float r = 1.0f / (1.0f + expf(-pr));
        float z = 1.0f / (1.0f + expf(-pz));
        float nn = tanhf(in_ + r * hn);
        float hv = (1.0f - z) * nn + z * hold_r[i][reg][gl];
        Ap[r_loc * 72 + (wc * 2 + gl) * 16 + l16] = f2b(hv);
      }
    }
  __syncthreads();
  {
    // 128 rows x 64 dims (128B/row): 1024 x 16B chunks, 2 per thread.
    #pragma unroll
    for (int c2 = 0; c2 < 2; ++c2) {
      int chunk = tid + 512 * c2;
      int row = chunk >> 3, sub = chunk & 7;
      *(uint4*)(h_out + (size_t)(m0 + row) * 128 + (n0 >> 2) + sub * 8) =
          *(const uint4*)&Ap[row * 72 + sub * 8];
    }
  }
}

// partial pooling over dense bf16 h: grid (graph, chunk); 8-way atomic max.
__global__ __launch_bounds__(128) void pool_kernel(const ushort_t* __restrict__ h,
    const int* __restrict__ gids, float* __restrict__ pooled, float* __restrict__ gcnt) {
  __shared__ int lo_s, hi_s;
  int g = blockIdx.x, c = blockIdx.y, d = threadIdx.x;
  if (d == 0) {
    int lo = 0, hi = N_NODES;
    while (lo < hi) { int mid = (lo + hi) >> 1; if (gids[mid] < g) lo = mid + 1; else hi = mid; }
    lo_s = lo;
    int lo2 = lo, hi2 = N_NODES;
    while (lo2 < hi2) { int mid = (lo2 + hi2) >> 1; if (gids[mid] < g + 1) lo2 = mid + 1; else hi2 = mid; }
    hi_s = lo2;
  }
  __syncthreads();
  int lo = lo_s, hi = hi_s;
  int len = hi - lo;
  int b = lo + (int)(((long long)len * c) >> 3);
  int e = lo + (int)(((long long)len * (c + 1)) >> 3);
  float s = 0.f;
  for (int n = b; n < e; ++n) s += b2f(h[(size_t)n * 128 + d]);
  if (e > b) atomicAdd(&pooled[g * 128 + d], s);
  if (c == 0 && d == 0) gcnt[g] = (float)len;
}

__global__ __launch_bounds__(256) void classifier_kernel(
    const float* __restrict__ pooled, const float* __restrict__ gcnt,
    const float* __restrict__ W1, const float* __restrict__ b1,
    const float* __restrict__ W2, const float* __restrict__ b2,
    float* __restrict__ out) {
  __shared__ float p[D];
  __shared__ float hid[256];
  __shared__ float wsum[4];
  int g = blockIdx.x;
  int t = threadIdx.x;
  float cnt = fmaxf(gcnt[g], 1.0f);
  if (t < D) p[t] = pooled[g * D + t] / cnt;
  __syncthreads();
  float acc = b1[t];
  const float* w = W1 + (size_t)t * D;
  for (int k = 0; k < D; ++k) acc += p[k] * w[k];
  hid[t] = fmaxf(acc, 0.0f);
  __syncthreads();
  float v = hid[t] * W2[t];
  for (int off = 32; off > 0; off >>= 1) v += __shfl_down(v, off, 64);
  if ((t & 63) == 0) wsum[t >> 6] = v;
  __syncthreads();
  if (t == 0) {
    float s = wsum[0] + wsum[1] + wsum[2] + wsum[3] + b2[0];
    out[g] = 1.0f / (1.0f + expf(-s));
  }
}

extern "C" void kernel_launch(void* const* d_in, const int* in_sizes, int n_in,
                              void* d_out, int out_size, void* d_ws, size_t ws_size,
                              hipStream_t stream) {
  const float* features = (const float*)d_in[0];
  const int* esrc  = (const int*)d_in[1];
  const int* edst  = (const int*)d_in[2];
  const int* etype = (const int*)d_in[3];
  const int* gids  = (const int*)d_in[4];
  const float* W_msg = (const float*)d_in[5];
  const float* b_msg = (const float*)d_in[6];
  const float* W_ih  = (const float*)d_in[7];
  const float* W_hh  = (const float*)d_in[8];
  const float* b_ih  = (const float*)d_in[9];
  const float* b_hh  = (const float*)d_in[10];
  const float* W1 = (const float*)d_in[11];
  const float* b1 = (const float*)d_in[12];
  const float* W2 = (const float*)d_in[13];
  const float* b2 = (const float*)d_in[14];
  float* out = (float*)d_out;

  char* ws = (char*)d_ws;
  size_t off_b = 0;
  auto alloc = [&](size_t bytes) -> void* {
    void* p = ws + off_b;
    off_b += (bytes + 255) & ~(size_t)255;
    return p;
  };
  ushort_t* hA     = (ushort_t*)alloc((size_t)M_PAD * 128 * 2);   // dense h
  ushort_t* hB     = (ushort_t*)alloc((size_t)M_PAD * 128 * 2);   // ping-pong
  ushort_t* aArr   = (ushort_t*)alloc((size_t)M_PAD * 128 * 2);   // dense a
  ushort_t* S      = (ushort_t*)alloc((size_t)M_PAD * 512 * 2);   // 51.2 MB bf16
  float*    cntf   = (float*)alloc((size_t)M_PAD * 4 * 4);        // per-node type counts
  ushort_t* BtS    = (ushort_t*)alloc(128 * 512 * 2);
  ushort_t* WgT    = (ushort_t*)alloc(512 * 256 * 2);
  float*    gbias  = (float*)alloc(512 * 4);
  int*      cnt2   = (int*)alloc((size_t)NBINS * 4);
  int*      offs2  = (int*)alloc((size_t)(NBINS + 1) * 4);
  int*      rank   = (int*)alloc((size_t)N_EDGES * 4);
  int*      tmp    = (int*)alloc((size_t)SCAN_BLOCKS * 1024 * 4);
  int*      bsum   = (int*)alloc(SCAN_BLOCKS * 4);
  int*      bpre   = (int*)alloc(SCAN_BLOCKS * 4);
  int*      payload= (int*)alloc((size_t)N_EDGES * 4);
  float*    pooled = (float*)alloc(N_GRAPHS * 128 * 4);
  float*    gcnt   = (float*)alloc(N_GRAPHS * 4);

  // ---- prologue ----
  pad_cast_kernel<<<(N_NODES * 128 + 255) / 256, 256, 0, stream>>>(features, hA);
  prep_bts<<<(128 * 512 + 255) / 256, 256, 0, stream>>>(W_msg, BtS);
  prep_wg<<<(512 * 256 + 255) / 256, 256, 0, stream>>>(W_ih, W_hh, b_ih, b_hh, WgT, gbias);
  hipMemsetAsync(cnt2, 0, (size_t)NBINS * 4, stream);
  hist_kernel<<<(N_EDGES + 255) / 256, 256, 0, stream>>>(edst, etype, cnt2, rank);
  scanA<<<SCAN_BLOCKS, 1024, 0, stream>>>(cnt2, tmp, bsum);
  scanB<<<1, 64, 0, stream>>>(bsum, bpre);
  scanC<<<SCAN_BLOCKS, 1024, 0, stream>>>(tmp, bpre, offs2);
  fill_kernel<<<(N_EDGES + 255) / 256, 256, 0, stream>>>(esrc, edst, etype, offs2, rank, payload);

  ushort_t* hc = hA;
  ushort_t* hn = hB;
  for (int step = 0; step < N_STEPS; ++step) {
    // S[n][t][:] = sum of h_src over type-t in-edges
    gather_kernel<<<(N_NODES + 3) / 4, 256, 0, stream>>>(offs2, payload, hc, S, cntf);
    // a = S @ [W_0;..;W_3] + cnt-weighted b_msg  (XCD-chunk-aligned with gru)
    mfma_msg<<<M_PAD / 128, 512, 0, stream>>>(S, BtS, b_msg, cntf, aArr);
    // GRU GEMM + gate epilogue (128x256 tile, flattened XCD grid of 782)
    mfma_gru<<<(M_PAD / 128) * 2, 512, 0, stream>>>(aArr, hc, WgT, gbias, hn);
    ushort_t* t2 = hc; hc = hn; hn = t2;
  }

  hipMemsetAsync(pooled, 0, (size_t)N_GRAPHS * 128 * 4, stream);
  pool_kernel<<<dim3(N_GRAPHS, 8), 128, 0, stream>>>(hc, gids, pooled, gcnt);
  classifier_kernel<<<N_GRAPHS, 256, 0, stream>>>(pooled, gcnt, W1, b1, W2, b2, out);
}

// Round 11
// 863.251 us; speedup vs baseline: 1.0435x; 1.0435x over previous
//
#include <hip/hip_runtime.h>
#include <hip/hip_bf16.h>
#include <math.h>

#define N_NODES 50000
#define M_PAD   50048   // 782 * 64 = 391 * 128
#define N_EDGES 800000
#define N_GRAPHS 100
#define IN_DIM 100
#define D 128
#define N_STEPS 8
#define NBINS (N_NODES * 4)      // (dst, type) bins
#define SCAN_BLOCKS 196          // 196*1024 = 200704 >= NBINS

typedef unsigned short ushort_t;
typedef __bf16 bf16x8 __attribute__((ext_vector_type(8)));
typedef float f32x4 __attribute__((ext_vector_type(4)));

__device__ inline ushort_t f2b(float f) {
  __hip_bfloat16 b = __float2bfloat16(f);
  return *reinterpret_cast<ushort_t*>(&b);
}
__device__ inline float b2f(unsigned int u16) {
  unsigned int x = u16 << 16;
  return __builtin_bit_cast(float, x);
}

// async global->LDS, 16B per lane; lds dest = wave-uniform base + lane*16.
__device__ __attribute__((always_inline)) inline void gld16(const ushort_t* g, ushort_t* l) {
  __builtin_amdgcn_global_load_lds(
      (const __attribute__((address_space(1))) void*)g,
      (__attribute__((address_space(3))) void*)l, 16, 0, 0);
}

// Dense bf16 state arrays h[N][128], a[N][128] (256B rows).
// Rounds 16 & 18 proved fusion regresses (barrier coupling / collapsed block
// parallelism on latency-bound kernels). Keep 3-kernel step structure.
__global__ void pad_cast_kernel(const float* __restrict__ feat, ushort_t* __restrict__ h) {
  int idx = blockIdx.x * blockDim.x + threadIdx.x;
  if (idx >= N_NODES * D) return;
  int n = idx >> 7, d = idx & 127;
  float v = (d < IN_DIM) ? feat[n * IN_DIM + d] : 0.0f;
  h[(size_t)n * 128 + d] = f2b(v);
}

// BtS[f][t*128+k] = bf16(W_msg[t][k][f])   (n-major, k-contiguous, K=512)
__global__ void prep_bts(const float* __restrict__ W_msg, ushort_t* __restrict__ BtS) {
  int idx = blockIdx.x * blockDim.x + threadIdx.x;
  if (idx >= 128 * 512) return;
  int f = idx >> 9, kp = idx & 511;
  int t = kp >> 7, k = kp & 127;
  BtS[(size_t)f * 512 + kp] = f2b(W_msg[((size_t)t * 128 + k) * 128 + f]);
}

// Permuted fused GRU weight, n-major k-contiguous bf16.
// col' = g*64 + gate*16 + r ; dim d = g*16 + r ; K: k<128 = a (W_ih), k>=128 = h (W_hh)
__global__ void prep_wg(const float* __restrict__ W_ih, const float* __restrict__ W_hh,
                        const float* __restrict__ b_ih, const float* __restrict__ b_hh,
                        ushort_t* __restrict__ WgT, float* __restrict__ gbias) {
  int idx = blockIdx.x * blockDim.x + threadIdx.x;
  if (idx >= 512 * 256) return;
  int colp = idx >> 8, k = idx & 255;
  int g = colp >> 6, gate = (colp >> 4) & 3, r = colp & 15;
  int d = g * 16 + r;
  float v;
  if (gate == 3)      v = (k < 128) ? 0.f : W_hh[(size_t)(256 + d) * 128 + (k - 128)];
  else if (gate == 2) v = (k < 128) ? W_ih[(size_t)(256 + d) * 128 + k] : 0.f;
  else {
    int j0 = (gate == 0) ? d : 128 + d;
    v = (k < 128) ? W_ih[(size_t)j0 * 128 + k] : W_hh[(size_t)j0 * 128 + (k - 128)];
  }
  WgT[(size_t)colp * 256 + k] = f2b(v);
  if (k == 0) {
    float bb = (gate == 0) ? b_ih[d] + b_hh[d]
             : (gate == 1) ? b_ih[128 + d] + b_hh[128 + d]
             : (gate == 2) ? b_ih[256 + d] : b_hh[256 + d];
    gbias[colp] = bb;
  }
}

// ---- type-segmented CSR build over NBINS = dst*4+type ----
__global__ void hist_kernel(const int* __restrict__ edst, const int* __restrict__ etype,
                            int* __restrict__ cnt2, int* __restrict__ rank) {
  int e = blockIdx.x * 256 + threadIdx.x;
  if (e >= N_EDGES) return;
  rank[e] = atomicAdd(&cnt2[edst[e] * 4 + etype[e]], 1);
}

// 3-phase scan: A) per-block inclusive scan + block sums
__global__ __launch_bounds__(1024) void scanA(const int* __restrict__ cnt2,
                                              int* __restrict__ tmp, int* __restrict__ bsum) {
  __shared__ int wsum[16];
  int b = blockIdx.x, t = threadIdx.x;
  int i = b * 1024 + t;
  int lane = t & 63, wid = t >> 6;
  int x = (i < NBINS) ? cnt2[i] : 0;
  #pragma unroll
  for (int s = 1; s < 64; s <<= 1) {
    int y = __shfl_up(x, s, 64);
    if (lane >= s) x += y;
  }
  if (lane == 63) wsum[wid] = x;
  __syncthreads();
  if (wid == 0) {
    int w = (lane < 16) ? wsum[lane] : 0;
    #pragma unroll
    for (int s = 1; s < 16; s <<= 1) {
      int y = __shfl_up(w, s, 64);
      if (lane >= s) w += y;
    }
    if (lane < 16) wsum[lane] = w;
  }
  __syncthreads();
  int wb = (wid > 0) ? wsum[wid - 1] : 0;
  tmp[i] = wb + x;
  if (t == 1023) bsum[b] = wsum[15];
}

// B) one wave scans the SCAN_BLOCKS block sums -> exclusive prefixes
__global__ __launch_bounds__(64) void scanB(const int* __restrict__ bsum,
                                            int* __restrict__ bpre) {
  int lane = threadIdx.x;
  int carry = 0;
  for (int base = 0; base < SCAN_BLOCKS; base += 64) {
    int idx = base + lane;
    int v = (idx < SCAN_BLOCKS) ? bsum[idx] : 0;
    int x = v;
    #pragma unroll
    for (int s = 1; s < 64; s <<= 1) {
      int y = __shfl_up(x, s, 64);
      if (lane >= s) x += y;
    }
    if (idx < SCAN_BLOCKS) bpre[idx] = carry + x - v;
    carry += __shfl(x, 63, 64);
  }
}

// C) offs2[i+1] = tmp[i] + bpre[block]
__global__ __launch_bounds__(1024) void scanC(const int* __restrict__ tmp,
                                              const int* __restrict__ bpre,
                                              int* __restrict__ offs2) {
  int b = blockIdx.x, t = threadIdx.x;
  int i = b * 1024 + t;
  if (i < NBINS) offs2[i + 1] = tmp[i] + bpre[b];
  if (i == 0) offs2[0] = 0;
}

__global__ void fill_kernel(const int* __restrict__ esrc, const int* __restrict__ edst,
                            const int* __restrict__ etype, const int* __restrict__ offs2,
                            const int* __restrict__ rank, int* __restrict__ payload) {
  int e = blockIdx.x * 256 + threadIdx.x;
  if (e >= N_EDGES) return;
  int key = edst[e] * 4 + etype[e];
  payload[offs2[key] + rank[e]] = esrc[e];
}

// ROUND-6 gather, FROZEN. One wave per node, 12500 tiny blocks. Three failed
// variants: r16/r18 fusion (barrier coupling kills MLP), r21 persistent grid
// (lost churn-based load balancing: occupancy 61->54, dur +2us). The tiny
// blocks ARE the load balancer. At the random-access ceiling. Do not touch.
__global__ __launch_bounds__(256) void gather_kernel(const int* __restrict__ offs2,
    const int* __restrict__ payload, const ushort_t* __restrict__ hb,
    ushort_t* __restrict__ S, float* __restrict__ cntf) {
  int n = blockIdx.x * 4 + (threadIdx.x >> 6);
  int lane = threadIdx.x & 63;
  if (n >= N_NODES) return;
  int bb[5];
  #pragma unroll
  for (int k = 0; k < 5; ++k) bb[k] = offs2[n * 4 + k];
  float a[4][2] = {{0.f, 0.f}, {0.f, 0.f}, {0.f, 0.f}, {0.f, 0.f}};
  const ushort_t* hrow = hb + lane * 2;
  for (int base = bb[0]; base < bb[4]; base += 64) {
    int lim = min(bb[4], base + 64);
    int cnt = lim - base;
    int pe = (lane < cnt) ? payload[base + lane] : 0;
    #pragma unroll
    for (int t = 0; t < 4; ++t) {
      int lo = max(bb[t], base), hi = min(bb[t + 1], lim);
      int i = lo;
      for (; i + 4 <= hi; i += 4) {
        int s0 = __shfl(pe, i - base, 64);
        int s1 = __shfl(pe, i + 1 - base, 64);
        int s2 = __shfl(pe, i + 2 - base, 64);
        int s3 = __shfl(pe, i + 3 - base, 64);
        unsigned int u0 = *(const unsigned int*)(hrow + (size_t)s0 * 128);
        unsigned int u1 = *(const unsigned int*)(hrow + (size_t)s1 * 128);
        unsigned int u2 = *(const unsigned int*)(hrow + (size_t)s2 * 128);
        unsigned int u3 = *(const unsigned int*)(hrow + (size_t)s3 * 128);
        a[t][0] += b2f(u0 & 0xffff) + b2f(u1 & 0xffff) + b2f(u2 & 0xffff) + b2f(u3 & 0xffff);
        a[t][1] += b2f(u0 >> 16) + b2f(u1 >> 16) + b2f(u2 >> 16) + b2f(u3 >> 16);
      }
      for (; i < hi; ++i) {
        int s0 = __shfl(pe, i - base, 64);
        unsigned int u0 = *(const unsigned int*)(hrow + (size_t)s0 * 128);
        a[t][0] += b2f(u0 & 0xffff);
        a[t][1] += b2f(u0 >> 16);
      }
    }
  }
  #pragma unroll
  for (int t = 0; t < 4; ++t) {
    unsigned int packed = (unsigned int)f2b(a[t][0]) | ((unsigned int)f2b(a[t][1]) << 16);
    *(unsigned int*)(S + (size_t)n * 512 + t * 128 + lane * 2) = packed;
    if (lane == 0) cntf[n * 4 + t] = (float)(bb[t + 1] - bb[t]);
  }
}

// ---- msg GEMM: 128(M)x128(N) tile, 8 waves (512 thr), K=512 (round 19). ----
// XCD chunk swizzle (391 = 8*48+7) aligning each XCD's a-writes with the
// m-chunks the gru on that XCD will read (a = 1.6 MB/XCD -> L2-resident).
__global__ __launch_bounds__(512, 4) void mfma_msg(
    const ushort_t* __restrict__ S,
    const ushort_t* __restrict__ Bt,
    const float* __restrict__ b_msg, const float* __restrict__ cntf,
    ushort_t* __restrict__ a_out) {
  constexpr int K = 512;
  constexpr int NT  = K / 32;     // 16 k-steps
  constexpr int PRE = 3;
  constexpr int SLOT = 16384;
  __shared__ __align__(16) unsigned char smem[SLOT * 4];   // 64 KB
  int orig = blockIdx.x;
  int xcd = orig & 7, sidx = orig >> 3;
  int wgb = (xcd < 7) ? (xcd * 49 + sidx) : (343 + sidx);
  const int m0 = wgb * 128;
  int tid = threadIdx.x;
  int wave = tid >> 6, lane = tid & 63;
  int wm = (wave & 3) * 32, wn = (wave >> 2) * 64;
  int quad = lane >> 4, l16 = lane & 15;

  int sr = lane >> 2, sc = lane & 3;
  const ushort_t* gA = S  + (size_t)(m0 + wave * 16 + sr) * K + sc * 8;
  const ushort_t* gB = Bt + (size_t)(wave * 16 + sr) * K + sc * 8;

  auto stage = [&](int slot, int t) {
    ushort_t* base = (ushort_t*)(smem + slot * SLOT);
    int k0 = t * 32;
    gld16(gA + k0, base + wave * 512);            // A rows wave*16..+16
    gld16(gB + k0, base + 4096 + wave * 512);     // B rows wave*16..+16
  };

  f32x4 acc[2][4];
  #pragma unroll
  for (int i = 0; i < 2; ++i)
    #pragma unroll
    for (int j = 0; j < 4; ++j) acc[i][j] = (f32x4){0.f, 0.f, 0.f, 0.f};

  #pragma unroll
  for (int t = 0; t < PRE; ++t) stage(t, t);

  #pragma unroll
  for (int t = 0; t < NT; ++t) {
    int infl = NT - 1 - t;
    if (infl >= 2)      asm volatile("s_waitcnt vmcnt(4) lgkmcnt(0)" ::: "memory");
    else if (infl == 1) asm volatile("s_waitcnt vmcnt(2) lgkmcnt(0)" ::: "memory");
    else                asm volatile("s_waitcnt vmcnt(0) lgkmcnt(0)" ::: "memory");
    __builtin_amdgcn_s_barrier();
    if (t + PRE < NT) stage((t + PRE) & 3, t + PRE);
    const ushort_t* As = (const ushort_t*)(smem + (t & 3) * SLOT);
    const ushort_t* Bs = As + 4096;
    bf16x8 af[2], bfr[4];
    #pragma unroll
    for (int i = 0; i < 2; ++i) af[i] = *(const bf16x8*)&As[(wm + i * 16 + l16) * 32 + quad * 8];
    #pragma unroll
    for (int j = 0; j < 4; ++j) bfr[j] = *(const bf16x8*)&Bs[(wn + j * 16 + l16) * 32 + quad * 8];
    #pragma unroll
    for (int i = 0; i < 2; ++i)
      #pragma unroll
      for (int j = 0; j < 4; ++j)
        acc[i][j] = __builtin_amdgcn_mfma_f32_16x16x32_bf16(af[i], bfr[j], acc[i][j], 0, 0, 0);
  }
  // Ep spans 34.8KB (slots 0-2): safe -- at last-iter entry lgkmcnt(0)+barrier
  // drained all reads of tiles <= NT-2; in-flight ds_reads target slot 3 only.
  ushort_t* Ep = (ushort_t*)smem;   // [128][136]
  float bm[4][4];  // [j][t]
  #pragma unroll
  for (int j = 0; j < 4; ++j)
    #pragma unroll
    for (int t = 0; t < 4; ++t)
      bm[j][t] = b_msg[t * 128 + wn + j * 16 + l16];
  #pragma unroll
  for (int i = 0; i < 2; ++i)
    #pragma unroll
    for (int reg = 0; reg < 4; ++reg) {
      int row = wm + i * 16 + quad * 4 + reg;
      float4 c = *(const float4*)(cntf + (size_t)(m0 + row) * 4);
      #pragma unroll
      for (int j = 0; j < 4; ++j) {
        float val = acc[i][j][reg] + c.x * bm[j][0] + c.y * bm[j][1]
                                   + c.z * bm[j][2] + c.w * bm[j][3];
        Ep[row * 136 + wn + j * 16 + l16] = f2b(val);
      }
    }
  __syncthreads();
  #pragma unroll
  for (int c2 = 0; c2 < 4; ++c2) {
    int chunk = tid + 512 * c2;            // 2048 x 16B = 128 rows x 256B
    int row = chunk >> 4, sub = chunk & 15;
    *(uint4*)(a_out + (size_t)(m0 + row) * 128 + sub * 8) =
        *(const uint4*)&Ep[row * 136 + sub * 8];
  }
}

// ---- ROUND-25 GRU GEMM: revert to the ROUND-22 form (best verified, 869.8).
// 128x128 tile, 8 waves, K=256, 3-slot ring (48KB) + PRE=2: 3 blocks/CU =
// 24 waves/CU. Round-23/24's 128x256 widening REGRESSED (+31us total:
// 72KB LDS -> 2 blocks/CU, 782-block grid tail -- exposed staging latency).
// Tile space is now fully explored: 64^2 < 128x256 < 128^2. Do not retry.
// vmcnt: 2 loads/step, 1 tile in flight -> steady vmcnt(2), tail 0.
// K-ORDER PERMUTED per block (k-sum order-independent): a-tiles 0-3 first,
// then the 3 other h-tiles, the NEEDED h-tile (4 + n0/128) LAST -> lands in
// slot (NT-1)%3 = 1 at exit; h_old read from there (kills a 12.8MB scattered
// fetch). XCD-chunk swizzle (1564=8*195+4).
__global__ __launch_bounds__(512, 4) void mfma_gru(
    const ushort_t* __restrict__ Aa, const ushort_t* __restrict__ Ah,
    const ushort_t* __restrict__ Bt,
    const float* __restrict__ bias,
    ushort_t* __restrict__ h_out) {
  constexpr int K = 256;
  constexpr int NT  = K / 32;     // 8 k-steps
  constexpr int SLOT = 16384;
  __shared__ __align__(16) unsigned char smem[SLOT * 3];   // 48 KB
  // XCD-chunk swizzle over 1564 blocks: q=195, r=4.
  int orig = blockIdx.x;
  int xcd = orig & 7, idxb = orig >> 3;
  int wgid = (xcd < 4 ? xcd * 196 : 4 * 196 + (xcd - 4) * 195) + idxb;
  const int m0 = (wgid >> 2) * 128, n0 = (wgid & 3) * 128;
  int tid = threadIdx.x;
  int wave = tid >> 6, lane = tid & 63;
  int wm = (wave & 3) * 32, wn = (wave >> 2) * 64;
  int quad = lane >> 4, l16 = lane & 15;
  const int q = n0 >> 7;   // which h k-tile this block's epilogue needs

  int sr = lane >> 2, sc = lane & 3;
  const ushort_t* gAa = Aa + (size_t)(m0 + wave * 16 + sr) * 128 + sc * 8;
  const ushort_t* gAh = Ah + (size_t)(m0 + wave * 16 + sr) * 128 + sc * 8;
  const ushort_t* gB  = Bt + (size_t)(n0 + wave * 16 + sr) * K + sc * 8;

  // permuted k order: t<4 -> a-tile t; t=4..6 -> h-tiles != q (ascending);
  // t=7 -> h-tile q.  (block-uniform)
  auto kglob = [&](int t) -> int {
    if (t < 4) return t;
    if (t == 7) return 4 + q;
    int v = t - 4;
    return 4 + v + (v >= q ? 1 : 0);
  };

  auto stage = [&](int slot, int t) {
    ushort_t* base = (ushort_t*)(smem + slot * SLOT);
    int kg = kglob(t);
    const ushort_t* srcA = (kg < 4) ? (gAa + kg * 32) : (gAh + (kg - 4) * 32);
    gld16(srcA, base + wave * 512);
    gld16(gB + kg * 32, base + 4096 + wave * 512);
  };

  f32x4 acc[2][4];
  #pragma unroll
  for (int i = 0; i < 2; ++i)
    #pragma unroll
    for (int j = 0; j < 4; ++j) acc[i][j] = (f32x4){0.f, 0.f, 0.f, 0.f};

  stage(0, 0);
  stage(1, 1);

  #pragma unroll
  for (int t = 0; t < NT; ++t) {
    if (t < NT - 1) asm volatile("s_waitcnt vmcnt(2) lgkmcnt(0)" ::: "memory");
    else            asm volatile("s_waitcnt vmcnt(0) lgkmcnt(0)" ::: "memory");
    __builtin_amdgcn_s_barrier();
    if (t + 2 < NT) stage((t + 2) % 3, t + 2);
    const ushort_t* As = (const ushort_t*)(smem + (t % 3) * SLOT);
    const ushort_t* Bs = As + 4096;
    bf16x8 af[2], bfr[4];
    #pragma unroll
    for (int i = 0; i < 2; ++i) af[i] = *(const bf16x8*)&As[(wm + i * 16 + l16) * 32 + quad * 8];
    #pragma unroll
    for (int j = 0; j < 4; ++j) bfr[j] = *(const bf16x8*)&Bs[(wn + j * 16 + l16) * 32 + quad * 8];
    #pragma unroll
    for (int i = 0; i < 2; ++i)
      #pragma unroll
      for (int j = 0; j < 4; ++j)
        acc[i][j] = __builtin_amdgcn_mfma_f32_16x16x32_bf16(af[i], bfr[j], acc[i][j], 0, 0, 0);
  }

  // h_old from LDS: last iteration (t=NT-1, the needed h-tile) sits in slot
  // (NT-1)%3 = 1; its A-region holds h cols [q*32, q*32+32) for all 128 rows.
  int wc = wave >> 2;
  const ushort_t* Hs = (const ushort_t*)(smem + ((NT - 1) % 3) * SLOT);
  float hold_r[2][4];
  #pragma unroll
  for (int i = 0; i < 2; ++i)
    #pragma unroll
    for (int reg = 0; reg < 4; ++reg) {
      int r_loc = wm + i * 16 + quad * 4 + reg;
      hold_r[i][reg] = b2f(Hs[r_loc * 32 + wc * 16 + l16]);
    }
  asm volatile("s_waitcnt lgkmcnt(0)" ::: "memory");
  __builtin_amdgcn_s_barrier();   // all h_old reads done before Ap overwrites

  // GRU gate epilogue; h_new staged in Ap (slot 0) then 64B-row stores.
  ushort_t* Ap = (ushort_t*)smem;                 // [128][40] = 10240 B
  float br = bias[n0 + wn + l16];
  float bz = bias[n0 + wn + 16 + l16];
  float bi = bias[n0 + wn + 32 + l16];
  float bh = bias[n0 + wn + 48 + l16];
  #pragma unroll
  for (int i = 0; i < 2; ++i)
    #pragma unroll
    for (int reg = 0; reg < 4; ++reg) {
      int r_loc = wm + i * 16 + quad * 4 + reg;
      float pr  = acc[i][0][reg] + br;
      float pz  = acc[i][1][reg] + bz;
      float in_ = acc[i][2][reg] + bi;
      float hn  = acc[i][3][reg] + bh;
      float r = 1.0f / (1.0f + expf(-pr));
      float z = 1.0f / (1.0f + expf(-pz));
      float nn = tanhf(in_ + r * hn);
      float hv = (1.0f - z) * nn + z * hold_r[i][reg];
      Ap[r_loc * 40 + wc * 16 + l16] = f2b(hv);
    }
  __syncthreads();
  {
    int row = tid >> 2, sub = tid & 3;       // 512 x 16B = 128 rows x 64B
    *(uint4*)(h_out + (size_t)(m0 + row) * 128 + (n0 >> 2) + sub * 8) =
        *(const uint4*)&Ap[row * 40 + sub * 8];
  }
}

// partial pooling over dense bf16 h: grid (graph, chunk); 8-way atomic max.
__global__ __launch_bounds__(128) void pool_kernel(const ushort_t* __restrict__ h,
    const int* __restrict__ gids, float* __restrict__ pooled, float* __restrict__ gcnt) {
  __shared__ int lo_s, hi_s;
  int g = blockIdx.x, c = blockIdx.y, d = threadIdx.x;
  if (d == 0) {
    int lo = 0, hi = N_NODES;
    while (lo < hi) { int mid = (lo + hi) >> 1; if (gids[mid] < g) lo = mid + 1; else hi = mid; }
    lo_s = lo;
    int lo2 = lo, hi2 = N_NODES;
    while (lo2 < hi2) { int mid = (lo2 + hi2) >> 1; if (gids[mid] < g + 1) lo2 = mid + 1; else hi2 = mid; }
    hi_s = lo2;
  }
  __syncthreads();
  int lo = lo_s, hi = hi_s;
  int len = hi - lo;
  int b = lo + (int)(((long long)len * c) >> 3);
  int e = lo + (int)(((long long)len * (c + 1)) >> 3);
  float s = 0.f;
  for (int n = b; n < e; ++n) s += b2f(h[(size_t)n * 128 + d]);
  if (e > b) atomicAdd(&pooled[g * 128 + d], s);
  if (c == 0 && d == 0) gcnt[g] = (float)len;
}

__global__ __launch_bounds__(256) void classifier_kernel(
    const float* __restrict__ pooled, const float* __restrict__ gcnt,
    const float* __restrict__ W1, const float* __restrict__ b1,
    const float* __restrict__ W2, const float* __restrict__ b2,
    float* __restrict__ out) {
  __shared__ float p[D];
  __shared__ float hid[256];
  __shared__ float wsum[4];
  int g = blockIdx.x;
  int t = threadIdx.x;
  float cnt = fmaxf(gcnt[g], 1.0f);
  if (t < D) p[t] = pooled[g * D + t] / cnt;
  __syncthreads();
  float acc = b1[t];
  const float* w = W1 + (size_t)t * D;
  for (int k = 0; k < D; ++k) acc += p[k] * w[k];
  hid[t] = fmaxf(acc, 0.0f);
  __syncthreads();
  float v = hid[t] * W2[t];
  for (int off = 32; off > 0; off >>= 1) v += __shfl_down(v, off, 64);
  if ((t & 63) == 0) wsum[t >> 6] = v;
  __syncthreads();
  if (t == 0) {
    float s = wsum[0] + wsum[1] + wsum[2] + wsum[3] + b2[0];
    out[g] = 1.0f / (1.0f + expf(-s));
  }
}

extern "C" void kernel_launch(void* const* d_in, const int* in_sizes, int n_in,
                              void* d_out, int out_size, void* d_ws, size_t ws_size,
                              hipStream_t stream) {
  const float* features = (const float*)d_in[0];
  const int* esrc  = (const int*)d_in[1];
  const int* edst  = (const int*)d_in[2];
  const int* etype = (const int*)d_in[3];
  const int* gids  = (const int*)d_in[4];
  const float* W_msg = (const float*)d_in[5];
  const float* b_msg = (const float*)d_in[6];
  const float* W_ih  = (const float*)d_in[7];
  const float* W_hh  = (const float*)d_in[8];
  const float* b_ih  = (const float*)d_in[9];
  const float* b_hh  = (const float*)d_in[10];
  const float* W1 = (const float*)d_in[11];
  const float* b1 = (const float*)d_in[12];
  const float* W2 = (const float*)d_in[13];
  const float* b2 = (const float*)d_in[14];
  float* out = (float*)d_out;

  char* ws = (char*)d_ws;
  size_t off_b = 0;
  auto alloc = [&](size_t bytes) -> void* {
    void* p = ws + off_b;
    off_b += (bytes + 255) & ~(size_t)255;
    return p;
  };
  ushort_t* hA     = (ushort_t*)alloc((size_t)M_PAD * 128 * 2);   // dense h
  ushort_t* hB     = (ushort_t*)alloc((size_t)M_PAD * 128 * 2);   // ping-pong
  ushort_t* aArr   = (ushort_t*)alloc((size_t)M_PAD * 128 * 2);   // dense a
  ushort_t* S      = (ushort_t*)alloc((size_t)M_PAD * 512 * 2);   // 51.2 MB bf16
  float*    cntf   = (float*)alloc((size_t)M_PAD * 4 * 4);        // per-node type counts
  ushort_t* BtS    = (ushort_t*)alloc(128 * 512 * 2);
  ushort_t* WgT    = (ushort_t*)alloc(512 * 256 * 2);
  float*    gbias  = (float*)alloc(512 * 4);
  int*      cnt2   = (int*)alloc((size_t)NBINS * 4);
  int*      offs2  = (int*)alloc((size_t)(NBINS + 1) * 4);
  int*      rank   = (int*)alloc((size_t)N_EDGES * 4);
  int*      tmp    = (int*)alloc((size_t)SCAN_BLOCKS * 1024 * 4);
  int*      bsum   = (int*)alloc(SCAN_BLOCKS * 4);
  int*      bpre   = (int*)alloc(SCAN_BLOCKS * 4);
  int*      payload= (int*)alloc((size_t)N_EDGES * 4);
  float*    pooled = (float*)alloc(N_GRAPHS * 128 * 4);
  float*    gcnt   = (float*)alloc(N_GRAPHS * 4);

  // ---- prologue ----
  pad_cast_kernel<<<(N_NODES * 128 + 255) / 256, 256, 0, stream>>>(features, hA);
  prep_bts<<<(128 * 512 + 255) / 256, 256, 0, stream>>>(W_msg, BtS);
  prep_wg<<<(512 * 256 + 255) / 256, 256, 0, stream>>>(W_ih, W_hh, b_ih, b_hh, WgT, gbias);
  hipMemsetAsync(cnt2, 0, (size_t)NBINS * 4, stream);
  hist_kernel<<<(N_EDGES + 255) / 256, 256, 0, stream>>>(edst, etype, cnt2, rank);
  scanA<<<SCAN_BLOCKS, 1024, 0, stream>>>(cnt2, tmp, bsum);
  scanB<<<1, 64, 0, stream>>>(bsum, bpre);
  scanC<<<SCAN_BLOCKS, 1024, 0, stream>>>(tmp, bpre, offs2);
  fill_kernel<<<(N_EDGES + 255) / 256, 256, 0, stream>>>(esrc, edst, etype, offs2, rank, payload);

  ushort_t* hc = hA;
  ushort_t* hn = hB;
  for (int step = 0; step < N_STEPS; ++step) {
    // S[n][t][:] = sum of h_src over type-t in-edges
    gather_kernel<<<(N_NODES + 3) / 4, 256, 0, stream>>>(offs2, payload, hc, S, cntf);
    // a = S @ [W_0;..;W_3] + cnt-weighted b_msg  (XCD-chunk-aligned with gru)
    mfma_msg<<<M_PAD / 128, 512, 0, stream>>>(S, BtS, b_msg, cntf, aArr);
    // GRU GEMM + gate epilogue (flattened XCD-swizzled grid of 1564)
    mfma_gru<<<(M_PAD / 128) * 4, 512, 0, stream>>>(aArr, hc, WgT, gbias, hn);
    ushort_t* t2 = hc; hc = hn; hn = t2;
  }

  hipMemsetAsync(pooled, 0, (size_t)N_GRAPHS * 128 * 4, stream);
  pool_kernel<<<dim3(N_GRAPHS, 8), 128, 0, stream>>>(hc, gids, pooled, gcnt);
  classifier_kernel<<<N_GRAPHS, 256, 0, stream>>>(pooled, gcnt, W1, b1, W2, b2, out);
}